// Round 18
// baseline (373.493 us; speedup 1.0000x reference)
//
#include <hip/hip_runtime.h>

// ---------- types / helpers ----------
typedef __attribute__((ext_vector_type(8))) short s16x8;
typedef __attribute__((ext_vector_type(4))) short s16x4;
typedef __attribute__((ext_vector_type(4))) float f32x4;

__device__ __forceinline__ f32x4 mfma16(s16x8 a, s16x8 b, f32x4 c) {
  return __builtin_amdgcn_mfma_f32_16x16x32_bf16(a, b, c, 0, 0, 0);
}
__device__ __forceinline__ f32x4 zero4() {
  f32x4 z = {0.f, 0.f, 0.f, 0.f};
  return z;
}

__device__ __forceinline__ unsigned short f2b(float f) {
  unsigned u = __float_as_uint(f);
  u = u + 0x7fffu + ((u >> 16) & 1u);          // RNE
  return (unsigned short)(u >> 16);
}
__device__ __forceinline__ float b2f(unsigned short u) {
  return __uint_as_float(((unsigned)u) << 16);
}
// pack two f32 -> two bf16 (RNE) in one uint
__device__ __forceinline__ unsigned packbf(float a, float b) {
  return (unsigned)f2b(a) | ((unsigned)f2b(b) << 16);
}

// direct global->LDS DMA, 16B per lane (dest must be wave-linear: base + lane*16)
__device__ __forceinline__ void gld16(const void* g, void* l) {
  __builtin_amdgcn_global_load_lds(
      (const __attribute__((address_space(1))) void*)g,
      (__attribute__((address_space(3))) void*)l, 16, 0, 0);
}

// problem constants
// B=16 S=512 H=16 DH=64 D=1024, BH=256

// ---------- K0 (merged): X conv + gate | W transpose x3 | dist_emb conv ----------
// blocks [0,8192): k0a  — X fp32 -> bf16 + per-head gate
// blocks [8192,8960): k0b — W [k][n] fp32 -> Wt [n][k] bf16 (16x16x3 tiles)
// blocks [8960,9216): k0c — dist_emb -> bf16 padded to 1024 rows
// (R14/R15 measured: ~-3.5 µs vs separate launches.)
__global__ __launch_bounds__(256) void k0_prep(
    const float* __restrict__ X, const float* __restrict__ gw,
    const float* __restrict__ gb, const float* __restrict__ Wq,
    const float* __restrict__ Wk, const float* __restrict__ Wv,
    const float* __restrict__ E, unsigned short* __restrict__ Xb,
    float* __restrict__ gate, unsigned short* __restrict__ Wt,
    unsigned short* __restrict__ Eb) {
  __shared__ float tile[64][68];   // used by k0b branch only
  int bid = blockIdx.x;
  int t = threadIdx.x;
  if (bid < 8192) {
    // ---- k0a ----
    int row = bid;
    const float* xr = X + (size_t)row * 1024;
    float4 x = *(const float4*)(xr + t * 4);
    s16x4 o;
    o.x = (short)f2b(x.x); o.y = (short)f2b(x.y);
    o.z = (short)f2b(x.z); o.w = (short)f2b(x.w);
    *(s16x4*)(&Xb[(size_t)row * 1024 + t * 4]) = o;
    int h = t >> 4;
    int e0 = (t & 15) * 4;
    const float* g4 = gw + h * 64 + e0;
    float part = x.x * g4[0] + x.y * g4[1] + x.z * g4[2] + x.w * g4[3];
    part += __shfl_xor(part, 1);
    part += __shfl_xor(part, 2);
    part += __shfl_xor(part, 4);
    part += __shfl_xor(part, 8);
    if ((t & 15) == 0) {
      int b = row >> 9, s = row & 511;
      float z = part + gb[h];
      gate[((size_t)(b * 16 + h)) * 512 + s] = 1.0f / (1.0f + __expf(-z));
    }
  } else if (bid < 8960) {
    // ---- k0b ----
    int i = bid - 8192;              // 768 = 16 x 16 x 3
    int zx = i & 15, zy = (i >> 4) & 15, z = i >> 8;
    const float* W = (z == 0) ? Wq : (z == 1) ? Wk : Wv;
    unsigned short* O = Wt + (size_t)z * 1024 * 1024;
    int k0 = zx * 64, n0 = zy * 64;
    int kl = t >> 4, nl = (t & 15) * 4;
#pragma unroll
    for (int p = 0; p < 4; ++p) {
      float4 v = *(const float4*)(W + (size_t)(k0 + p * 16 + kl) * 1024 + n0 + nl);
      tile[p * 16 + kl][nl + 0] = v.x;
      tile[p * 16 + kl][nl + 1] = v.y;
      tile[p * 16 + kl][nl + 2] = v.z;
      tile[p * 16 + kl][nl + 3] = v.w;
    }
    __syncthreads();
    for (int idx = t; idx < 4096; idx += 256) {
      int nl2 = idx >> 6, kl2 = idx & 63;
      O[(size_t)(n0 + nl2) * 1024 + k0 + kl2] = f2b(tile[kl2][nl2]);
    }
  } else {
    // ---- k0c ----
    int idx = (bid - 8960) * 256 + t;   // < 65536
    int row = idx >> 6;
    float v = (row < 1023) ? E[idx] : 0.0f;
    Eb[idx] = f2b(v);
  }
}

// ---------- K1: QKV GEMM  Xb[8192,1024] @ W -> Q/K bf16 [bh][s][dh], V -> Vt [bh][dh][s] ----------
// Staging via global_load_lds width=16 into UNPADDED [128][64] tiles (wave-linear dest).
// z==2 (V): vectorized direct store (R10). z in {0,1} (Q/K): epilogue routes acc
// through the dead 32KB staging LDS as a [128][128] bf16 tile, then stores 16B
// coalesced chunks.
__global__ __launch_bounds__(256) void k1_qkv(
    const unsigned short* __restrict__ Xb, const unsigned short* __restrict__ Wt,
    const float* __restrict__ bq, const float* __restrict__ bk,
    const float* __restrict__ bv, unsigned short* __restrict__ Qb,
    unsigned short* __restrict__ Kb, unsigned short* __restrict__ Vt) {
  __shared__ short SH[2 * 128 * 64];   // As | Ws staging; epilogue reuse: [128][128] tile
  short* As = SH;
  short* Ws = SH + 128 * 64;
  int t = threadIdx.x;
  int wv = t >> 6, lane = t & 63, quad = lane >> 4, l15 = lane & 15;
  int wm = wv >> 1, wn = wv & 1;
  // XCD swizzle over x (64 = 8*8): 8 consecutive logical m-tiles per XCD share the W panel
  int bx = blockIdx.x;
  bx = ((bx & 7) << 3) | (bx >> 3);
  int m0 = bx * 128, n0 = blockIdx.y * 128, z = blockIdx.z;
  const unsigned short* W = Wt + (size_t)z * 1024 * 1024;
  f32x4 acc[4][4];
#pragma unroll
  for (int i = 0; i < 4; ++i)
#pragma unroll
    for (int j = 0; j < 4; ++j) acc[i][j] = zero4();

  int srow = t >> 3, scg = t & 7;   // staging: row 0..127 (via +p*32), 8 lanes/row

  for (int kt = 0; kt < 16; ++kt) {
    int k0 = kt * 64;
    __syncthreads();
#pragma unroll
    for (int p = 0; p < 4; ++p) {
      int row = srow + p * 32;
      gld16(Xb + (size_t)(m0 + row) * 1024 + k0 + scg * 8, &As[row * 64 + scg * 8]);
      gld16(W + (size_t)(n0 + row) * 1024 + k0 + scg * 8, &Ws[row * 64 + scg * 8]);
    }
    __syncthreads();
#pragma unroll
    for (int ks = 0; ks < 2; ++ks) {
      s16x8 a[4], bb[4];
#pragma unroll
      for (int i = 0; i < 4; ++i)
        a[i] = *(const s16x8*)(&As[(wm * 64 + i * 16 + l15) * 64 + ks * 32 + quad * 8]);
#pragma unroll
      for (int j = 0; j < 4; ++j)
        bb[j] = *(const s16x8*)(&Ws[(wn * 64 + j * 16 + l15) * 64 + ks * 32 + quad * 8]);
#pragma unroll
      for (int i = 0; i < 4; ++i)
#pragma unroll
        for (int j = 0; j < 4; ++j)
          acc[i][j] = mfma16(a[i], bb[j], acc[i][j]);
    }
  }
  const float* bias = (z == 0) ? bq : (z == 1) ? bk : bv;
  if (z == 2) {
#pragma unroll
    for (int i = 0; i < 4; ++i) {
      int mbase = m0 + wm * 64 + i * 16 + quad * 4;
#pragma unroll
      for (int j = 0; j < 4; ++j) {
        int n = n0 + wn * 64 + j * 16 + l15;
        float bvv = bias[n];
        int h = n >> 6, dh = n & 63;
        int b = mbase >> 9, s = mbase & 511;
        s16x4 uv;
        uv.x = (short)f2b(acc[i][j][0] + bvv);
        uv.y = (short)f2b(acc[i][j][1] + bvv);
        uv.z = (short)f2b(acc[i][j][2] + bvv);
        uv.w = (short)f2b(acc[i][j][3] + bvv);
        *(s16x4*)(&Vt[(size_t)((b * 16 + h) * 64 + dh) * 512 + s]) = uv;
      }
    }
  } else {
    unsigned short* O = (z == 0) ? Qb : Kb;
    __syncthreads();               // all MFMA reads of As/Ws done (all waves)
    short* T = SH;                 // [128][128] bf16, exactly 32 KB
#pragma unroll
    for (int i = 0; i < 4; ++i) {
      int ml = wm * 64 + i * 16 + quad * 4;
#pragma unroll
      for (int j = 0; j < 4; ++j) {
        int nl = wn * 64 + j * 16 + l15;
        float bvv = bias[n0 + nl];
        T[(ml + 0) * 128 + nl] = (short)f2b(acc[i][j][0] + bvv);
        T[(ml + 1) * 128 + nl] = (short)f2b(acc[i][j][1] + bvv);
        T[(ml + 2) * 128 + nl] = (short)f2b(acc[i][j][2] + bvv);
        T[(ml + 3) * 128 + nl] = (short)f2b(acc[i][j][3] + bvv);
      }
    }
    __syncthreads();
    // coalesced write-out: 2048 chunks of 8 shorts (16B); wave emits 1KB contiguous
#pragma unroll
    for (int k = 0; k < 8; ++k) {
      int c = k * 256 + t;
      int ml = c >> 4, g = c & 15;
      int m = m0 + ml;
      int b = m >> 9, s = m & 511;
      int n = n0 + g * 8;
      int h = n >> 6, dh = n & 63;
      s16x8 v = *(const s16x8*)(&T[ml * 128 + g * 8]);
      *(s16x8*)(&O[(size_t)((b * 16 + h) * 512 + s) * 64 + dh]) = v;
    }
  }
}

// ---------- K2 v18: R17 body + Ss pad 68 -> 70 (odd dword row stride) ----------
// Bank-conflict arithmetic: Ss1 exp-phase read addr = tt*68 + dl, per-lane
// bank = C' + 10*quad - 2*l15 (mod 32) — the even l15-stride confines 64 lanes
// to 16 even banks = 4-way conflict (1.58x, m136). Measured 7.34M conflict
// cycles/dispatch ~= 12 µs/CU upper bound. Pad 70 shorts = 35 dwords (odd):
// read l15-stride becomes 3 (coprime 32) -> spread across all banks; writes go
// from 0-way to worst-case 2-way (free). Pure immediate-constant change — zero
// register impact (the R2-R9 failure mode was register-driven). LDS 44032 ->
// 45056, 3x45056 = 135168 <= 160 KiB: still 3 blocks/CU.
// Tripwires: conflicts not down, WRITE > 45 MB, or dur > 205 -> revert.
__global__ __launch_bounds__(256, 2) void k2_attn(
    const unsigned short* __restrict__ Qb, const unsigned short* __restrict__ Kb,
    const unsigned short* __restrict__ Vt, const unsigned short* __restrict__ Eb,
    const float* __restrict__ gate, const float* __restrict__ mask,
    float* __restrict__ out) {
  __shared__ short Ks[64 * 72];     // K tile (pass 1); aliased as Ps (epilogue)
  __shared__ short Ss1[128 * 70];   // Q@E^T col-major bf16 [dist 128][q 64+pad6]
  __shared__ short Ss2[128 * 70];   // K@E^T col-major bf16 [dist 128][k 64+pad6]

  int t = threadIdx.x;
  int wv = t >> 6, lane = t & 63, quad = lane >> 4, l15 = lane & 15;
  // XCD swizzle: 2048 blocks = 8 XCDs * 256; the 8 q-tiles of one bh land on one XCD
  int bid = ((blockIdx.x & 7) << 8) | (blockIdx.x >> 3);
  int bh = bid >> 3, qt = bid & 7;
  int b = bh >> 4, hh = bh & 15;
  int l0 = qt * 64;

  // staging indices for K tile (2 x int4 per thread)
  int srow = t >> 3, scg = t & 7;

  // Q A-frags for this wave's 16 q rows (constant all phases)
  s16x8 aq0, aq1;
  {
    const unsigned short* qp = Qb + ((size_t)bh * 512 + l0 + wv * 16 + l15) * 64 + quad * 8;
    aq0 = *(const s16x8*)(qp);
    aq1 = *(const s16x8*)(qp + 32);
  }

  float lsum[4];
#pragma unroll
  for (int r = 0; r < 4; ++r) lsum[r] = 0.0f;
  unsigned stash[64];   // [kt][nf][pair]: ex(r=0,1) and ex(r=2,3) packed bf16

  // ================= single pass: scores -> exp -> stash =================
#pragma unroll
  for (int kt = 0; kt < 8; ++kt) {
    int r0 = kt * 64;
    // prefetch K tile into regs (no LDS dependency yet)
    int4 kv0 = *(const int4*)(Kb + ((size_t)bh * 512 + r0 + srow) * 64 + scg * 8);
    int4 kv1 = *(const int4*)(Kb + ((size_t)bh * 512 + r0 + srow + 32) * 64 + scg * 8);
    // hoisted mask loads for this kt (consumed after the Ss barrier)
    float mkv[4];
#pragma unroll
    for (int nf = 0; nf < 4; ++nf)
      mkv[nf] = mask[b * 512 + kt * 64 + nf * 16 + l15];
    __syncthreads();   // prior tile's Ks/Ss readers done
    *(int4*)(&Ks[srow * 72 + scg * 8]) = kv0;
    *(int4*)(&Ks[(srow + 32) * 72 + scg * 8]) = kv1;
    // issue ALL 16 E B-frag loads here (kv dead; latency overlaps the barrier
    // drain + ak ds_reads; consumed by the MFMA burst below) — R16: -4.3 µs
    int estart = (qt - kt) * 64 + 448;
    s16x8 ebf[16];
#pragma unroll
    for (int nf = 0; nf < 8; ++nf) {
      const s16x8* ep = (const s16x8*)(Eb + (size_t)(estart + nf * 16 + l15) * 64 + quad * 8);
      ebf[nf * 2] = ep[0];
      ebf[nf * 2 + 1] = ep[4];
    }
    __syncthreads();   // Ks visible
    s16x8 ak0 = *(const s16x8*)(&Ks[(wv * 16 + l15) * 72 + quad * 8]);
    s16x8 ak1 = *(const s16x8*)(&Ks[(wv * 16 + l15) * 72 + 32 + quad * 8]);
    // S1 = Q@E^T, S2 = K@E^T -> LDS col-major bf16 (dense MFMA burst)
#pragma unroll
    for (int nf = 0; nf < 8; ++nf) {
      f32x4 s1 = mfma16(aq1, ebf[nf * 2 + 1], mfma16(aq0, ebf[nf * 2], zero4()));
      s16x4 w1;
      w1.x = (short)f2b(s1[0]); w1.y = (short)f2b(s1[1]);
      w1.z = (short)f2b(s1[2]); w1.w = (short)f2b(s1[3]);
      *(s16x4*)(&Ss1[(nf * 16 + l15) * 70 + wv * 16 + quad * 4]) = w1;
      f32x4 s2 = mfma16(ak1, ebf[nf * 2 + 1], mfma16(ak0, ebf[nf * 2], zero4()));
      s16x4 w2;
      w2.x = (short)f2b(s2[0]); w2.y = (short)f2b(s2[1]);
      w2.z = (short)f2b(s2[2]); w2.w = (short)f2b(s2[3]);
      *(s16x4*)(&Ss2[(nf * 16 + l15) * 70 + wv * 16 + quad * 4]) = w2;
    }
    // QK^T stripe
    f32x4 s[4];
#pragma unroll
    for (int nf = 0; nf < 4; ++nf) {
      s16x8 b0 = *(const s16x8*)(&Ks[(nf * 16 + l15) * 72 + quad * 8]);
      s16x8 b1 = *(const s16x8*)(&Ks[(nf * 16 + l15) * 72 + 32 + quad * 8]);
      s[nf] = mfma16(aq1, b1, mfma16(aq0, b0, zero4()));
    }
    __syncthreads();   // Ss visible
#pragma unroll
    for (int nf = 0; nf < 4; ++nf) {
      int dr = nf * 16 + l15;
      float ex[4];
#pragma unroll
      for (int r = 0; r < 4; ++r) {
        int dl = wv * 16 + quad * 4 + r;
        int tt = dl - dr + 63;   // 0..126
        float p1 = b2f((unsigned short)Ss1[tt * 70 + dl]);
        float p2 = b2f((unsigned short)Ss2[tt * 70 + dr]);
        float x = (s[nf][r] + p1 + p2) * 0.125f + mkv[nf];
        ex[r] = __expf(x);
        lsum[r] += ex[r];
      }
      stash[kt * 8 + nf * 2 + 0] = packbf(ex[0], ex[1]);
      stash[kt * 8 + nf * 2 + 1] = packbf(ex[2], ex[3]);
    }
  }

  // cross-lane (l15 group) combine of row sums
#pragma unroll
  for (int r = 0; r < 4; ++r) {
    lsum[r] += __shfl_xor(lsum[r], 1);
    lsum[r] += __shfl_xor(lsum[r], 2);
    lsum[r] += __shfl_xor(lsum[r], 4);
    lsum[r] += __shfl_xor(lsum[r], 8);
  }
  float f1[4];
#pragma unroll
  for (int r = 0; r < 4; ++r) f1[r] = 1.0234375f / lsum[r];
  const float c0 = -0.0234375f;

  // ================= epilogue: p = clip(ex*f1 + c0) -> Ps -> P@V =================
  // Ps aliases Ks: Ks's last readers (kt=7 QK^T B-frags) are before the kt=7
  // "Ss visible" barrier, which every wave has passed. Ps is wave-local.
  short* Ps = Ks;

  f32x4 ctx[4];
#pragma unroll
  for (int nf = 0; nf < 4; ++nf) ctx[nf] = zero4();

#pragma unroll
  for (int kt = 0; kt < 8; ++kt) {
    // V B-frag loads first (loop-constant addresses; latency covered by the
    // stash-unpack/clip/Ps-store VALU block below)
    s16x8 vb0[4], vb1[4];
#pragma unroll
    for (int nf = 0; nf < 4; ++nf) {
      const s16x8* vp = (const s16x8*)(Vt + ((size_t)bh * 64 + nf * 16 + l15) * 512 + kt * 64 + quad * 8);
      vb0[nf] = vp[0];
      vb1[nf] = vp[4];
    }
#pragma unroll
    for (int nf = 0; nf < 4; ++nf) {
      unsigned u0 = stash[kt * 8 + nf * 2 + 0];
      unsigned u1 = stash[kt * 8 + nf * 2 + 1];
      float e0 = b2f((unsigned short)(u0 & 0xffff));
      float e1 = b2f((unsigned short)(u0 >> 16));
      float e2 = b2f((unsigned short)(u1 & 0xffff));
      float e3 = b2f((unsigned short)(u1 >> 16));
      float p0 = fminf(fmaxf(e0 * f1[0] + c0, 0.0f), 1.0f);
      float p1 = fminf(fmaxf(e1 * f1[1] + c0, 0.0f), 1.0f);
      float p2 = fminf(fmaxf(e2 * f1[2] + c0, 0.0f), 1.0f);
      float p3 = fminf(fmaxf(e3 * f1[3] + c0, 0.0f), 1.0f);
      int rowb = wv * 16 + quad * 4;
      Ps[(rowb + 0) * 72 + nf * 16 + l15] = (short)f2b(p0);
      Ps[(rowb + 1) * 72 + nf * 16 + l15] = (short)f2b(p1);
      Ps[(rowb + 2) * 72 + nf * 16 + l15] = (short)f2b(p2);
      Ps[(rowb + 3) * 72 + nf * 16 + l15] = (short)f2b(p3);
    }
    // P@V for this tile (wave-local Ps)
    s16x8 ap0 = *(const s16x8*)(&Ps[(wv * 16 + l15) * 72 + quad * 8]);
    s16x8 ap1 = *(const s16x8*)(&Ps[(wv * 16 + l15) * 72 + 32 + quad * 8]);
#pragma unroll
    for (int nf = 0; nf < 4; ++nf)
      ctx[nf] = mfma16(ap1, vb1[nf], mfma16(ap0, vb0[nf], ctx[nf]));
  }

  // ---- epilogue: * gate, write out [b][s][h*64+dh] fp32 ----
#pragma unroll
  for (int r = 0; r < 4; ++r) {
    int s = l0 + wv * 16 + quad * 4 + r;
    float g = gate[(size_t)bh * 512 + s];
#pragma unroll
    for (int nf = 0; nf < 4; ++nf)
      out[((size_t)(b * 512 + s)) * 1024 + hh * 64 + nf * 16 + l15] = ctx[nf][r] * g;
  }
}

// ---------- launch ----------
extern "C" void kernel_launch(void* const* d_in, const int* in_sizes, int n_in,
                              void* d_out, int out_size, void* d_ws, size_t ws_size,
                              hipStream_t stream) {
  const float* X = (const float*)d_in[0];
  const float* mask = (const float*)d_in[1];
  const float* Wq = (const float*)d_in[2];
  const float* bq = (const float*)d_in[3];
  const float* Wk = (const float*)d_in[4];
  const float* bk = (const float*)d_in[5];
  const float* Wv = (const float*)d_in[6];
  const float* bv = (const float*)d_in[7];
  const float* dist = (const float*)d_in[8];
  const float* gw = (const float*)d_in[9];
  const float* gb = (const float*)d_in[10];
  float* out = (float*)d_out;

  char* ws = (char*)d_ws;
  constexpr size_t OFF_XB = 0;                       // 8192*1024*2 = 16 MB
  constexpr size_t OFF_WT = 16777216;                // 3*1024*1024*2 = 6 MB
  constexpr size_t OFF_QB = OFF_WT + 6291456;        // 16 MB
  constexpr size_t OFF_KB = OFF_QB + 16777216;       // 16 MB
  constexpr size_t OFF_VT = OFF_KB + 16777216;       // 16 MB
  constexpr size_t OFF_EB = OFF_VT + 16777216;       // 1024*64*2
  constexpr size_t OFF_GA = OFF_EB + 131072;         // 256*512*4

  unsigned short* Xb = (unsigned short*)(ws + OFF_XB);
  unsigned short* Wt = (unsigned short*)(ws + OFF_WT);
  unsigned short* Qb = (unsigned short*)(ws + OFF_QB);
  unsigned short* Kb = (unsigned short*)(ws + OFF_KB);
  unsigned short* Vt = (unsigned short*)(ws + OFF_VT);
  unsigned short* Eb = (unsigned short*)(ws + OFF_EB);
  float* gate = (float*)(ws + OFF_GA);

  hipLaunchKernelGGL(k0_prep, dim3(9216), dim3(256), 0, stream,
                     X, gw, gb, Wq, Wk, Wv, dist, Xb, gate, Wt, Eb);
  hipLaunchKernelGGL(k1_qkv, dim3(64, 8, 3), dim3(256), 0, stream,
                     Xb, Wt, bq, bk, bv, Qb, Kb, Vt);
  hipLaunchKernelGGL(k2_attn, dim3(2048), dim3(256), 0, stream,
                     Qb, Kb, Vt, Eb, gate, mask, out);
}

// Round 19
// 364.658 us; speedup vs baseline: 1.0242x; 1.0242x over previous
//
#include <hip/hip_runtime.h>

// ---------- types / helpers ----------
typedef __attribute__((ext_vector_type(8))) short s16x8;
typedef __attribute__((ext_vector_type(4))) short s16x4;
typedef __attribute__((ext_vector_type(4))) float f32x4;

__device__ __forceinline__ f32x4 mfma16(s16x8 a, s16x8 b, f32x4 c) {
  return __builtin_amdgcn_mfma_f32_16x16x32_bf16(a, b, c, 0, 0, 0);
}
__device__ __forceinline__ f32x4 zero4() {
  f32x4 z = {0.f, 0.f, 0.f, 0.f};
  return z;
}

__device__ __forceinline__ unsigned short f2b(float f) {
  unsigned u = __float_as_uint(f);
  u = u + 0x7fffu + ((u >> 16) & 1u);          // RNE
  return (unsigned short)(u >> 16);
}
__device__ __forceinline__ float b2f(unsigned short u) {
  return __uint_as_float(((unsigned)u) << 16);
}
// pack two f32 -> two bf16 (RNE) in one uint
__device__ __forceinline__ unsigned packbf(float a, float b) {
  return (unsigned)f2b(a) | ((unsigned)f2b(b) << 16);
}

// direct global->LDS DMA, 16B per lane (dest must be wave-linear: base + lane*16)
__device__ __forceinline__ void gld16(const void* g, void* l) {
  __builtin_amdgcn_global_load_lds(
      (const __attribute__((address_space(1))) void*)g,
      (__attribute__((address_space(3))) void*)l, 16, 0, 0);
}

// problem constants
// B=16 S=512 H=16 DH=64 D=1024, BH=256

// ---------- K0 (merged): X conv + gate | W transpose x3 | dist_emb conv ----------
// blocks [0,8192): k0a  — X fp32 -> bf16 + per-head gate
// blocks [8192,8960): k0b — W [k][n] fp32 -> Wt [n][k] bf16 (16x16x3 tiles)
// blocks [8960,9216): k0c — dist_emb -> bf16 padded to 1024 rows
// (R14/R15 measured: ~-3.5 µs vs separate launches.)
__global__ __launch_bounds__(256) void k0_prep(
    const float* __restrict__ X, const float* __restrict__ gw,
    const float* __restrict__ gb, const float* __restrict__ Wq,
    const float* __restrict__ Wk, const float* __restrict__ Wv,
    const float* __restrict__ E, unsigned short* __restrict__ Xb,
    float* __restrict__ gate, unsigned short* __restrict__ Wt,
    unsigned short* __restrict__ Eb) {
  __shared__ float tile[64][68];   // used by k0b branch only
  int bid = blockIdx.x;
  int t = threadIdx.x;
  if (bid < 8192) {
    // ---- k0a ----
    int row = bid;
    const float* xr = X + (size_t)row * 1024;
    float4 x = *(const float4*)(xr + t * 4);
    s16x4 o;
    o.x = (short)f2b(x.x); o.y = (short)f2b(x.y);
    o.z = (short)f2b(x.z); o.w = (short)f2b(x.w);
    *(s16x4*)(&Xb[(size_t)row * 1024 + t * 4]) = o;
    int h = t >> 4;
    int e0 = (t & 15) * 4;
    const float* g4 = gw + h * 64 + e0;
    float part = x.x * g4[0] + x.y * g4[1] + x.z * g4[2] + x.w * g4[3];
    part += __shfl_xor(part, 1);
    part += __shfl_xor(part, 2);
    part += __shfl_xor(part, 4);
    part += __shfl_xor(part, 8);
    if ((t & 15) == 0) {
      int b = row >> 9, s = row & 511;
      float z = part + gb[h];
      gate[((size_t)(b * 16 + h)) * 512 + s] = 1.0f / (1.0f + __expf(-z));
    }
  } else if (bid < 8960) {
    // ---- k0b ----
    int i = bid - 8192;              // 768 = 16 x 16 x 3
    int zx = i & 15, zy = (i >> 4) & 15, z = i >> 8;
    const float* W = (z == 0) ? Wq : (z == 1) ? Wk : Wv;
    unsigned short* O = Wt + (size_t)z * 1024 * 1024;
    int k0 = zx * 64, n0 = zy * 64;
    int kl = t >> 4, nl = (t & 15) * 4;
#pragma unroll
    for (int p = 0; p < 4; ++p) {
      float4 v = *(const float4*)(W + (size_t)(k0 + p * 16 + kl) * 1024 + n0 + nl);
      tile[p * 16 + kl][nl + 0] = v.x;
      tile[p * 16 + kl][nl + 1] = v.y;
      tile[p * 16 + kl][nl + 2] = v.z;
      tile[p * 16 + kl][nl + 3] = v.w;
    }
    __syncthreads();
    for (int idx = t; idx < 4096; idx += 256) {
      int nl2 = idx >> 6, kl2 = idx & 63;
      O[(size_t)(n0 + nl2) * 1024 + k0 + kl2] = f2b(tile[kl2][nl2]);
    }
  } else {
    // ---- k0c ----
    int idx = (bid - 8960) * 256 + t;   // < 65536
    int row = idx >> 6;
    float v = (row < 1023) ? E[idx] : 0.0f;
    Eb[idx] = f2b(v);
  }
}

// ---------- K1: QKV GEMM  Xb[8192,1024] @ W -> Q/K bf16 [bh][s][dh], V -> Vt [bh][dh][s] ----------
// Staging via global_load_lds width=16 into UNPADDED [128][64] tiles (wave-linear dest).
// z==2 (V): vectorized direct store (R10). z in {0,1} (Q/K): epilogue routes acc
// through the dead 32KB staging LDS as a [128][128] bf16 tile, then stores 16B
// coalesced chunks.
__global__ __launch_bounds__(256) void k1_qkv(
    const unsigned short* __restrict__ Xb, const unsigned short* __restrict__ Wt,
    const float* __restrict__ bq, const float* __restrict__ bk,
    const float* __restrict__ bv, unsigned short* __restrict__ Qb,
    unsigned short* __restrict__ Kb, unsigned short* __restrict__ Vt) {
  __shared__ short SH[2 * 128 * 64];   // As | Ws staging; epilogue reuse: [128][128] tile
  short* As = SH;
  short* Ws = SH + 128 * 64;
  int t = threadIdx.x;
  int wv = t >> 6, lane = t & 63, quad = lane >> 4, l15 = lane & 15;
  int wm = wv >> 1, wn = wv & 1;
  // XCD swizzle over x (64 = 8*8): 8 consecutive logical m-tiles per XCD share the W panel
  int bx = blockIdx.x;
  bx = ((bx & 7) << 3) | (bx >> 3);
  int m0 = bx * 128, n0 = blockIdx.y * 128, z = blockIdx.z;
  const unsigned short* W = Wt + (size_t)z * 1024 * 1024;
  f32x4 acc[4][4];
#pragma unroll
  for (int i = 0; i < 4; ++i)
#pragma unroll
    for (int j = 0; j < 4; ++j) acc[i][j] = zero4();

  int srow = t >> 3, scg = t & 7;   // staging: row 0..127 (via +p*32), 8 lanes/row

  for (int kt = 0; kt < 16; ++kt) {
    int k0 = kt * 64;
    __syncthreads();
#pragma unroll
    for (int p = 0; p < 4; ++p) {
      int row = srow + p * 32;
      gld16(Xb + (size_t)(m0 + row) * 1024 + k0 + scg * 8, &As[row * 64 + scg * 8]);
      gld16(W + (size_t)(n0 + row) * 1024 + k0 + scg * 8, &Ws[row * 64 + scg * 8]);
    }
    __syncthreads();
#pragma unroll
    for (int ks = 0; ks < 2; ++ks) {
      s16x8 a[4], bb[4];
#pragma unroll
      for (int i = 0; i < 4; ++i)
        a[i] = *(const s16x8*)(&As[(wm * 64 + i * 16 + l15) * 64 + ks * 32 + quad * 8]);
#pragma unroll
      for (int j = 0; j < 4; ++j)
        bb[j] = *(const s16x8*)(&Ws[(wn * 64 + j * 16 + l15) * 64 + ks * 32 + quad * 8]);
#pragma unroll
      for (int i = 0; i < 4; ++i)
#pragma unroll
        for (int j = 0; j < 4; ++j)
          acc[i][j] = mfma16(a[i], bb[j], acc[i][j]);
    }
  }
  const float* bias = (z == 0) ? bq : (z == 1) ? bk : bv;
  if (z == 2) {
#pragma unroll
    for (int i = 0; i < 4; ++i) {
      int mbase = m0 + wm * 64 + i * 16 + quad * 4;
#pragma unroll
      for (int j = 0; j < 4; ++j) {
        int n = n0 + wn * 64 + j * 16 + l15;
        float bvv = bias[n];
        int h = n >> 6, dh = n & 63;
        int b = mbase >> 9, s = mbase & 511;
        s16x4 uv;
        uv.x = (short)f2b(acc[i][j][0] + bvv);
        uv.y = (short)f2b(acc[i][j][1] + bvv);
        uv.z = (short)f2b(acc[i][j][2] + bvv);
        uv.w = (short)f2b(acc[i][j][3] + bvv);
        *(s16x4*)(&Vt[(size_t)((b * 16 + h) * 64 + dh) * 512 + s]) = uv;
      }
    }
  } else {
    unsigned short* O = (z == 0) ? Qb : Kb;
    __syncthreads();               // all MFMA reads of As/Ws done (all waves)
    short* T = SH;                 // [128][128] bf16, exactly 32 KB
#pragma unroll
    for (int i = 0; i < 4; ++i) {
      int ml = wm * 64 + i * 16 + quad * 4;
#pragma unroll
      for (int j = 0; j < 4; ++j) {
        int nl = wn * 64 + j * 16 + l15;
        float bvv = bias[n0 + nl];
        T[(ml + 0) * 128 + nl] = (short)f2b(acc[i][j][0] + bvv);
        T[(ml + 1) * 128 + nl] = (short)f2b(acc[i][j][1] + bvv);
        T[(ml + 2) * 128 + nl] = (short)f2b(acc[i][j][2] + bvv);
        T[(ml + 3) * 128 + nl] = (short)f2b(acc[i][j][3] + bvv);
      }
    }
    __syncthreads();
    // coalesced write-out: 2048 chunks of 8 shorts (16B); wave emits 1KB contiguous
#pragma unroll
    for (int k = 0; k < 8; ++k) {
      int c = k * 256 + t;
      int ml = c >> 4, g = c & 15;
      int m = m0 + ml;
      int b = m >> 9, s = m & 511;
      int n = n0 + g * 8;
      int h = n >> 6, dh = n & 63;
      s16x8 v = *(const s16x8*)(&T[ml * 128 + g * 8]);
      *(s16x8*)(&O[(size_t)((b * 16 + h) * 512 + s) * 64 + dh]) = v;
    }
  }
}

// ---------- K2 v16 (R16, byte-exact — session best, FROZEN) ----------
// 195 µs verified. Structure: 3-barrier kt loop, batched-E with issue hoisted
// above the Ks-visible barrier (R16: -4.3 µs), Ps aliases Ks, mask hoist,
// XCD swizzle, pad-68 Ss (R18: pad-70 DOUBLED conflicts — ds_write_b64 2-bank
// width tiles perfectly at even stride; do not touch). Register-cliff: the
// allocator won't cross the 128-VGPR step; any kt-loop pressure growth spills
// stash[64] (R2/R3/R4/R6/R9). setprio hurts (R14); barrier-merge hurts (R11);
// epilogue vp-hoist is a compiler no-op (R17).
__global__ __launch_bounds__(256, 2) void k2_attn(
    const unsigned short* __restrict__ Qb, const unsigned short* __restrict__ Kb,
    const unsigned short* __restrict__ Vt, const unsigned short* __restrict__ Eb,
    const float* __restrict__ gate, const float* __restrict__ mask,
    float* __restrict__ out) {
  __shared__ short Ks[64 * 72];     // K tile (pass 1); aliased as Ps (epilogue)
  __shared__ short Ss1[128 * 68];   // Q@E^T col-major bf16 [dist 128][q 64+pad]
  __shared__ short Ss2[128 * 68];   // K@E^T col-major bf16 [dist 128][k 64+pad]

  int t = threadIdx.x;
  int wv = t >> 6, lane = t & 63, quad = lane >> 4, l15 = lane & 15;
  // XCD swizzle: 2048 blocks = 8 XCDs * 256; the 8 q-tiles of one bh land on one XCD
  int bid = ((blockIdx.x & 7) << 8) | (blockIdx.x >> 3);
  int bh = bid >> 3, qt = bid & 7;
  int b = bh >> 4, hh = bh & 15;
  int l0 = qt * 64;

  // staging indices for K tile (2 x int4 per thread)
  int srow = t >> 3, scg = t & 7;

  // Q A-frags for this wave's 16 q rows (constant all phases)
  s16x8 aq0, aq1;
  {
    const unsigned short* qp = Qb + ((size_t)bh * 512 + l0 + wv * 16 + l15) * 64 + quad * 8;
    aq0 = *(const s16x8*)(qp);
    aq1 = *(const s16x8*)(qp + 32);
  }

  float lsum[4];
#pragma unroll
  for (int r = 0; r < 4; ++r) lsum[r] = 0.0f;
  unsigned stash[64];   // [kt][nf][pair]: ex(r=0,1) and ex(r=2,3) packed bf16

  // ================= single pass: scores -> exp -> stash =================
#pragma unroll
  for (int kt = 0; kt < 8; ++kt) {
    int r0 = kt * 64;
    // prefetch K tile into regs (no LDS dependency yet)
    int4 kv0 = *(const int4*)(Kb + ((size_t)bh * 512 + r0 + srow) * 64 + scg * 8);
    int4 kv1 = *(const int4*)(Kb + ((size_t)bh * 512 + r0 + srow + 32) * 64 + scg * 8);
    // hoisted mask loads for this kt (consumed after the Ss barrier)
    float mkv[4];
#pragma unroll
    for (int nf = 0; nf < 4; ++nf)
      mkv[nf] = mask[b * 512 + kt * 64 + nf * 16 + l15];
    __syncthreads();   // prior tile's Ks/Ss readers done
    *(int4*)(&Ks[srow * 72 + scg * 8]) = kv0;
    *(int4*)(&Ks[(srow + 32) * 72 + scg * 8]) = kv1;
    // issue ALL 16 E B-frag loads here (kv dead; latency overlaps the barrier
    // drain + ak ds_reads; consumed by the MFMA burst below) — R16: -4.3 µs
    int estart = (qt - kt) * 64 + 448;
    s16x8 ebf[16];
#pragma unroll
    for (int nf = 0; nf < 8; ++nf) {
      const s16x8* ep = (const s16x8*)(Eb + (size_t)(estart + nf * 16 + l15) * 64 + quad * 8);
      ebf[nf * 2] = ep[0];
      ebf[nf * 2 + 1] = ep[4];
    }
    __syncthreads();   // Ks visible
    s16x8 ak0 = *(const s16x8*)(&Ks[(wv * 16 + l15) * 72 + quad * 8]);
    s16x8 ak1 = *(const s16x8*)(&Ks[(wv * 16 + l15) * 72 + 32 + quad * 8]);
    // S1 = Q@E^T, S2 = K@E^T -> LDS col-major bf16 (dense MFMA burst)
#pragma unroll
    for (int nf = 0; nf < 8; ++nf) {
      f32x4 s1 = mfma16(aq1, ebf[nf * 2 + 1], mfma16(aq0, ebf[nf * 2], zero4()));
      s16x4 w1;
      w1.x = (short)f2b(s1[0]); w1.y = (short)f2b(s1[1]);
      w1.z = (short)f2b(s1[2]); w1.w = (short)f2b(s1[3]);
      *(s16x4*)(&Ss1[(nf * 16 + l15) * 68 + wv * 16 + quad * 4]) = w1;
      f32x4 s2 = mfma16(ak1, ebf[nf * 2 + 1], mfma16(ak0, ebf[nf * 2], zero4()));
      s16x4 w2;
      w2.x = (short)f2b(s2[0]); w2.y = (short)f2b(s2[1]);
      w2.z = (short)f2b(s2[2]); w2.w = (short)f2b(s2[3]);
      *(s16x4*)(&Ss2[(nf * 16 + l15) * 68 + wv * 16 + quad * 4]) = w2;
    }
    // QK^T stripe
    f32x4 s[4];
#pragma unroll
    for (int nf = 0; nf < 4; ++nf) {
      s16x8 b0 = *(const s16x8*)(&Ks[(nf * 16 + l15) * 72 + quad * 8]);
      s16x8 b1 = *(const s16x8*)(&Ks[(nf * 16 + l15) * 72 + 32 + quad * 8]);
      s[nf] = mfma16(aq1, b1, mfma16(aq0, b0, zero4()));
    }
    __syncthreads();   // Ss visible
#pragma unroll
    for (int nf = 0; nf < 4; ++nf) {
      int dr = nf * 16 + l15;
      float ex[4];
#pragma unroll
      for (int r = 0; r < 4; ++r) {
        int dl = wv * 16 + quad * 4 + r;
        int tt = dl - dr + 63;   // 0..126
        float p1 = b2f((unsigned short)Ss1[tt * 68 + dl]);
        float p2 = b2f((unsigned short)Ss2[tt * 68 + dr]);
        float x = (s[nf][r] + p1 + p2) * 0.125f + mkv[nf];
        ex[r] = __expf(x);
        lsum[r] += ex[r];
      }
      stash[kt * 8 + nf * 2 + 0] = packbf(ex[0], ex[1]);
      stash[kt * 8 + nf * 2 + 1] = packbf(ex[2], ex[3]);
    }
  }

  // cross-lane (l15 group) combine of row sums
#pragma unroll
  for (int r = 0; r < 4; ++r) {
    lsum[r] += __shfl_xor(lsum[r], 1);
    lsum[r] += __shfl_xor(lsum[r], 2);
    lsum[r] += __shfl_xor(lsum[r], 4);
    lsum[r] += __shfl_xor(lsum[r], 8);
  }
  float f1[4];
#pragma unroll
  for (int r = 0; r < 4; ++r) f1[r] = 1.0234375f / lsum[r];
  const float c0 = -0.0234375f;

  // ================= epilogue: p = clip(ex*f1 + c0) -> Ps -> P@V =================
  // Ps aliases Ks: Ks's last readers (kt=7 QK^T B-frags) are before the kt=7
  // "Ss visible" barrier, which every wave has passed. Ps is wave-local.
  short* Ps = Ks;

  f32x4 ctx[4];
#pragma unroll
  for (int nf = 0; nf < 4; ++nf) ctx[nf] = zero4();

#pragma unroll
  for (int kt = 0; kt < 8; ++kt) {
#pragma unroll
    for (int nf = 0; nf < 4; ++nf) {
      unsigned u0 = stash[kt * 8 + nf * 2 + 0];
      unsigned u1 = stash[kt * 8 + nf * 2 + 1];
      float e0 = b2f((unsigned short)(u0 & 0xffff));
      float e1 = b2f((unsigned short)(u0 >> 16));
      float e2 = b2f((unsigned short)(u1 & 0xffff));
      float e3 = b2f((unsigned short)(u1 >> 16));
      float p0 = fminf(fmaxf(e0 * f1[0] + c0, 0.0f), 1.0f);
      float p1 = fminf(fmaxf(e1 * f1[1] + c0, 0.0f), 1.0f);
      float p2 = fminf(fmaxf(e2 * f1[2] + c0, 0.0f), 1.0f);
      float p3 = fminf(fmaxf(e3 * f1[3] + c0, 0.0f), 1.0f);
      int rowb = wv * 16 + quad * 4;
      Ps[(rowb + 0) * 72 + nf * 16 + l15] = (short)f2b(p0);
      Ps[(rowb + 1) * 72 + nf * 16 + l15] = (short)f2b(p1);
      Ps[(rowb + 2) * 72 + nf * 16 + l15] = (short)f2b(p2);
      Ps[(rowb + 3) * 72 + nf * 16 + l15] = (short)f2b(p3);
    }
    // P@V for this tile (wave-local Ps; V B-frags direct from global)
    s16x8 ap0 = *(const s16x8*)(&Ps[(wv * 16 + l15) * 72 + quad * 8]);
    s16x8 ap1 = *(const s16x8*)(&Ps[(wv * 16 + l15) * 72 + 32 + quad * 8]);
#pragma unroll
    for (int nf = 0; nf < 4; ++nf) {
      const s16x8* vp = (const s16x8*)(Vt + ((size_t)bh * 64 + nf * 16 + l15) * 512 + kt * 64 + quad * 8);
      s16x8 vb0 = vp[0];
      s16x8 vb1 = vp[4];
      ctx[nf] = mfma16(ap1, vb1, mfma16(ap0, vb0, ctx[nf]));
    }
  }

  // ---- epilogue: * gate, write out [b][s][h*64+dh] fp32 ----
#pragma unroll
  for (int r = 0; r < 4; ++r) {
    int s = l0 + wv * 16 + quad * 4 + r;
    float g = gate[(size_t)bh * 512 + s];
#pragma unroll
    for (int nf = 0; nf < 4; ++nf)
      out[((size_t)(b * 512 + s)) * 1024 + hh * 64 + nf * 16 + l15] = ctx[nf][r] * g;
  }
}

// ---------- launch ----------
extern "C" void kernel_launch(void* const* d_in, const int* in_sizes, int n_in,
                              void* d_out, int out_size, void* d_ws, size_t ws_size,
                              hipStream_t stream) {
  const float* X = (const float*)d_in[0];
  const float* mask = (const float*)d_in[1];
  const float* Wq = (const float*)d_in[2];
  const float* bq = (const float*)d_in[3];
  const float* Wk = (const float*)d_in[4];
  const float* bk = (const float*)d_in[5];
  const float* Wv = (const float*)d_in[6];
  const float* bv = (const float*)d_in[7];
  const float* dist = (const float*)d_in[8];
  const float* gw = (const float*)d_in[9];
  const float* gb = (const float*)d_in[10];
  float* out = (float*)d_out;

  char* ws = (char*)d_ws;
  constexpr size_t OFF_XB = 0;                       // 8192*1024*2 = 16 MB
  constexpr size_t OFF_WT = 16777216;                // 3*1024*1024*2 = 6 MB
  constexpr size_t OFF_QB = OFF_WT + 6291456;        // 16 MB
  constexpr size_t OFF_KB = OFF_QB + 16777216;       // 16 MB
  constexpr size_t OFF_VT = OFF_KB + 16777216;       // 16 MB
  constexpr size_t OFF_EB = OFF_VT + 16777216;       // 1024*64*2
  constexpr size_t OFF_GA = OFF_EB + 131072;         // 256*512*4

  unsigned short* Xb = (unsigned short*)(ws + OFF_XB);
  unsigned short* Wt = (unsigned short*)(ws + OFF_WT);
  unsigned short* Qb = (unsigned short*)(ws + OFF_QB);
  unsigned short* Kb = (unsigned short*)(ws + OFF_KB);
  unsigned short* Vt = (unsigned short*)(ws + OFF_VT);
  unsigned short* Eb = (unsigned short*)(ws + OFF_EB);
  float* gate = (float*)(ws + OFF_GA);

  hipLaunchKernelGGL(k0_prep, dim3(9216), dim3(256), 0, stream,
                     X, gw, gb, Wq, Wk, Wv, dist, Xb, gate, Wt, Eb);
  hipLaunchKernelGGL(k1_qkv, dim3(64, 8, 3), dim3(256), 0, stream,
                     Xb, Wt, bq, bk, bv, Qb, Kb, Vt);
  hipLaunchKernelGGL(k2_attn, dim3(2048), dim3(256), 0, stream,
                     Qb, Kb, Vt, Eb, gate, mask, out);
}

// Round 20
// 364.451 us; speedup vs baseline: 1.0248x; 1.0006x over previous
//
#include <hip/hip_runtime.h>

// ---------- types / helpers ----------
typedef __attribute__((ext_vector_type(8))) short s16x8;
typedef __attribute__((ext_vector_type(4))) short s16x4;
typedef __attribute__((ext_vector_type(4))) float f32x4;

__device__ __forceinline__ f32x4 mfma16(s16x8 a, s16x8 b, f32x4 c) {
  return __builtin_amdgcn_mfma_f32_16x16x32_bf16(a, b, c, 0, 0, 0);
}
__device__ __forceinline__ f32x4 zero4() {
  f32x4 z = {0.f, 0.f, 0.f, 0.f};
  return z;
}

__device__ __forceinline__ unsigned short f2b(float f) {
  unsigned u = __float_as_uint(f);
  u = u + 0x7fffu + ((u >> 16) & 1u);          // RNE
  return (unsigned short)(u >> 16);
}
__device__ __forceinline__ float b2f(unsigned short u) {
  return __uint_as_float(((unsigned)u) << 16);
}
// pack two f32 -> two bf16 (RNE) in one uint
__device__ __forceinline__ unsigned packbf(float a, float b) {
  return (unsigned)f2b(a) | ((unsigned)f2b(b) << 16);
}

// direct global->LDS DMA, 16B per lane (dest must be wave-linear: base + lane*16)
__device__ __forceinline__ void gld16(const void* g, void* l) {
  __builtin_amdgcn_global_load_lds(
      (const __attribute__((address_space(1))) void*)g,
      (__attribute__((address_space(3))) void*)l, 16, 0, 0);
}

// problem constants
// B=16 S=512 H=16 DH=64 D=1024, BH=256

// ---------- K0 (merged): X conv + gate | W transpose x3 | dist_emb conv ----------
// blocks [0,8192): k0a  — X fp32 -> bf16 + per-head gate
// blocks [8192,8960): k0b — W [k][n] fp32 -> Wt [n][k] bf16 (16x16x3 tiles)
// blocks [8960,9216): k0c — dist_emb -> bf16 padded to 1024 rows
// (R14/R15 measured: ~-3.5 µs vs separate launches.)
__global__ __launch_bounds__(256) void k0_prep(
    const float* __restrict__ X, const float* __restrict__ gw,
    const float* __restrict__ gb, const float* __restrict__ Wq,
    const float* __restrict__ Wk, const float* __restrict__ Wv,
    const float* __restrict__ E, unsigned short* __restrict__ Xb,
    float* __restrict__ gate, unsigned short* __restrict__ Wt,
    unsigned short* __restrict__ Eb) {
  __shared__ float tile[64][68];   // used by k0b branch only
  int bid = blockIdx.x;
  int t = threadIdx.x;
  if (bid < 8192) {
    // ---- k0a ----
    int row = bid;
    const float* xr = X + (size_t)row * 1024;
    float4 x = *(const float4*)(xr + t * 4);
    s16x4 o;
    o.x = (short)f2b(x.x); o.y = (short)f2b(x.y);
    o.z = (short)f2b(x.z); o.w = (short)f2b(x.w);
    *(s16x4*)(&Xb[(size_t)row * 1024 + t * 4]) = o;
    int h = t >> 4;
    int e0 = (t & 15) * 4;
    const float* g4 = gw + h * 64 + e0;
    float part = x.x * g4[0] + x.y * g4[1] + x.z * g4[2] + x.w * g4[3];
    part += __shfl_xor(part, 1);
    part += __shfl_xor(part, 2);
    part += __shfl_xor(part, 4);
    part += __shfl_xor(part, 8);
    if ((t & 15) == 0) {
      int b = row >> 9, s = row & 511;
      float z = part + gb[h];
      gate[((size_t)(b * 16 + h)) * 512 + s] = 1.0f / (1.0f + __expf(-z));
    }
  } else if (bid < 8960) {
    // ---- k0b ----
    int i = bid - 8192;              // 768 = 16 x 16 x 3
    int zx = i & 15, zy = (i >> 4) & 15, z = i >> 8;
    const float* W = (z == 0) ? Wq : (z == 1) ? Wk : Wv;
    unsigned short* O = Wt + (size_t)z * 1024 * 1024;
    int k0 = zx * 64, n0 = zy * 64;
    int kl = t >> 4, nl = (t & 15) * 4;
#pragma unroll
    for (int p = 0; p < 4; ++p) {
      float4 v = *(const float4*)(W + (size_t)(k0 + p * 16 + kl) * 1024 + n0 + nl);
      tile[p * 16 + kl][nl + 0] = v.x;
      tile[p * 16 + kl][nl + 1] = v.y;
      tile[p * 16 + kl][nl + 2] = v.z;
      tile[p * 16 + kl][nl + 3] = v.w;
    }
    __syncthreads();
    for (int idx = t; idx < 4096; idx += 256) {
      int nl2 = idx >> 6, kl2 = idx & 63;
      O[(size_t)(n0 + nl2) * 1024 + k0 + kl2] = f2b(tile[kl2][nl2]);
    }
  } else {
    // ---- k0c ----
    int idx = (bid - 8960) * 256 + t;   // < 65536
    int row = idx >> 6;
    float v = (row < 1023) ? E[idx] : 0.0f;
    Eb[idx] = f2b(v);
  }
}

// ---------- K1: QKV GEMM  Xb[8192,1024] @ W -> Q/K bf16 [bh][s][dh], V -> Vt [bh][dh][s] ----------
// Staging via global_load_lds width=16 into UNPADDED [128][64] tiles (wave-linear dest).
// z==2 (V): vectorized direct store (R10). z in {0,1} (Q/K): epilogue routes acc
// through the dead 32KB staging LDS as a [128][128] bf16 tile, then stores 16B
// coalesced chunks.
__global__ __launch_bounds__(256) void k1_qkv(
    const unsigned short* __restrict__ Xb, const unsigned short* __restrict__ Wt,
    const float* __restrict__ bq, const float* __restrict__ bk,
    const float* __restrict__ bv, unsigned short* __restrict__ Qb,
    unsigned short* __restrict__ Kb, unsigned short* __restrict__ Vt) {
  __shared__ short SH[2 * 128 * 64];   // As | Ws staging; epilogue reuse: [128][128] tile
  short* As = SH;
  short* Ws = SH + 128 * 64;
  int t = threadIdx.x;
  int wv = t >> 6, lane = t & 63, quad = lane >> 4, l15 = lane & 15;
  int wm = wv >> 1, wn = wv & 1;
  // XCD swizzle over x (64 = 8*8): 8 consecutive logical m-tiles per XCD share the W panel
  int bx = blockIdx.x;
  bx = ((bx & 7) << 3) | (bx >> 3);
  int m0 = bx * 128, n0 = blockIdx.y * 128, z = blockIdx.z;
  const unsigned short* W = Wt + (size_t)z * 1024 * 1024;
  f32x4 acc[4][4];
#pragma unroll
  for (int i = 0; i < 4; ++i)
#pragma unroll
    for (int j = 0; j < 4; ++j) acc[i][j] = zero4();

  int srow = t >> 3, scg = t & 7;   // staging: row 0..127 (via +p*32), 8 lanes/row

  for (int kt = 0; kt < 16; ++kt) {
    int k0 = kt * 64;
    __syncthreads();
#pragma unroll
    for (int p = 0; p < 4; ++p) {
      int row = srow + p * 32;
      gld16(Xb + (size_t)(m0 + row) * 1024 + k0 + scg * 8, &As[row * 64 + scg * 8]);
      gld16(W + (size_t)(n0 + row) * 1024 + k0 + scg * 8, &Ws[row * 64 + scg * 8]);
    }
    __syncthreads();
#pragma unroll
    for (int ks = 0; ks < 2; ++ks) {
      s16x8 a[4], bb[4];
#pragma unroll
      for (int i = 0; i < 4; ++i)
        a[i] = *(const s16x8*)(&As[(wm * 64 + i * 16 + l15) * 64 + ks * 32 + quad * 8]);
#pragma unroll
      for (int j = 0; j < 4; ++j)
        bb[j] = *(const s16x8*)(&Ws[(wn * 64 + j * 16 + l15) * 64 + ks * 32 + quad * 8]);
#pragma unroll
      for (int i = 0; i < 4; ++i)
#pragma unroll
        for (int j = 0; j < 4; ++j)
          acc[i][j] = mfma16(a[i], bb[j], acc[i][j]);
    }
  }
  const float* bias = (z == 0) ? bq : (z == 1) ? bk : bv;
  if (z == 2) {
#pragma unroll
    for (int i = 0; i < 4; ++i) {
      int mbase = m0 + wm * 64 + i * 16 + quad * 4;
#pragma unroll
      for (int j = 0; j < 4; ++j) {
        int n = n0 + wn * 64 + j * 16 + l15;
        float bvv = bias[n];
        int h = n >> 6, dh = n & 63;
        int b = mbase >> 9, s = mbase & 511;
        s16x4 uv;
        uv.x = (short)f2b(acc[i][j][0] + bvv);
        uv.y = (short)f2b(acc[i][j][1] + bvv);
        uv.z = (short)f2b(acc[i][j][2] + bvv);
        uv.w = (short)f2b(acc[i][j][3] + bvv);
        *(s16x4*)(&Vt[(size_t)((b * 16 + h) * 64 + dh) * 512 + s]) = uv;
      }
    }
  } else {
    unsigned short* O = (z == 0) ? Qb : Kb;
    __syncthreads();               // all MFMA reads of As/Ws done (all waves)
    short* T = SH;                 // [128][128] bf16, exactly 32 KB
#pragma unroll
    for (int i = 0; i < 4; ++i) {
      int ml = wm * 64 + i * 16 + quad * 4;
#pragma unroll
      for (int j = 0; j < 4; ++j) {
        int nl = wn * 64 + j * 16 + l15;
        float bvv = bias[n0 + nl];
        T[(ml + 0) * 128 + nl] = (short)f2b(acc[i][j][0] + bvv);
        T[(ml + 1) * 128 + nl] = (short)f2b(acc[i][j][1] + bvv);
        T[(ml + 2) * 128 + nl] = (short)f2b(acc[i][j][2] + bvv);
        T[(ml + 3) * 128 + nl] = (short)f2b(acc[i][j][3] + bvv);
      }
    }
    __syncthreads();
    // coalesced write-out: 2048 chunks of 8 shorts (16B); wave emits 1KB contiguous
#pragma unroll
    for (int k = 0; k < 8; ++k) {
      int c = k * 256 + t;
      int ml = c >> 4, g = c & 15;
      int m = m0 + ml;
      int b = m >> 9, s = m & 511;
      int n = n0 + g * 8;
      int h = n >> 6, dh = n & 63;
      s16x8 v = *(const s16x8*)(&T[ml * 128 + g * 8]);
      *(s16x8*)(&O[(size_t)((b * 16 + h) * 512 + s) * 64 + dh]) = v;
    }
  }
}

// ---------- K2 v16 (R16/R19, byte-exact — session best, FROZEN) ----------
// 195 µs steady-state (365 µs total, best of session, twice reproduced).
// Structure: 3-barrier kt loop, batched-E with issue hoisted above the
// Ks-visible barrier (R16: -4.3 µs), Ps aliases Ks, mask hoist, XCD swizzle,
// pad-68 Ss (R18: pad-70 DOUBLED conflicts — ds_write_b64 2-bank width tiles
// perfectly at even stride). Register-cliff: allocator won't cross the
// 128-VGPR step; any kt-loop pressure growth spills stash[64] (R2/R3/R4/R6/
// R9). setprio hurts (R14); barrier-merge hurts (R11); epilogue vp-hoist is
// a compiler no-op (R17). Lever space exhausted — structural plateau.
__global__ __launch_bounds__(256, 2) void k2_attn(
    const unsigned short* __restrict__ Qb, const unsigned short* __restrict__ Kb,
    const unsigned short* __restrict__ Vt, const unsigned short* __restrict__ Eb,
    const float* __restrict__ gate, const float* __restrict__ mask,
    float* __restrict__ out) {
  __shared__ short Ks[64 * 72];     // K tile (pass 1); aliased as Ps (epilogue)
  __shared__ short Ss1[128 * 68];   // Q@E^T col-major bf16 [dist 128][q 64+pad]
  __shared__ short Ss2[128 * 68];   // K@E^T col-major bf16 [dist 128][k 64+pad]

  int t = threadIdx.x;
  int wv = t >> 6, lane = t & 63, quad = lane >> 4, l15 = lane & 15;
  // XCD swizzle: 2048 blocks = 8 XCDs * 256; the 8 q-tiles of one bh land on one XCD
  int bid = ((blockIdx.x & 7) << 8) | (blockIdx.x >> 3);
  int bh = bid >> 3, qt = bid & 7;
  int b = bh >> 4, hh = bh & 15;
  int l0 = qt * 64;

  // staging indices for K tile (2 x int4 per thread)
  int srow = t >> 3, scg = t & 7;

  // Q A-frags for this wave's 16 q rows (constant all phases)
  s16x8 aq0, aq1;
  {
    const unsigned short* qp = Qb + ((size_t)bh * 512 + l0 + wv * 16 + l15) * 64 + quad * 8;
    aq0 = *(const s16x8*)(qp);
    aq1 = *(const s16x8*)(qp + 32);
  }

  float lsum[4];
#pragma unroll
  for (int r = 0; r < 4; ++r) lsum[r] = 0.0f;
  unsigned stash[64];   // [kt][nf][pair]: ex(r=0,1) and ex(r=2,3) packed bf16

  // ================= single pass: scores -> exp -> stash =================
#pragma unroll
  for (int kt = 0; kt < 8; ++kt) {
    int r0 = kt * 64;
    // prefetch K tile into regs (no LDS dependency yet)
    int4 kv0 = *(const int4*)(Kb + ((size_t)bh * 512 + r0 + srow) * 64 + scg * 8);
    int4 kv1 = *(const int4*)(Kb + ((size_t)bh * 512 + r0 + srow + 32) * 64 + scg * 8);
    // hoisted mask loads for this kt (consumed after the Ss barrier)
    float mkv[4];
#pragma unroll
    for (int nf = 0; nf < 4; ++nf)
      mkv[nf] = mask[b * 512 + kt * 64 + nf * 16 + l15];
    __syncthreads();   // prior tile's Ks/Ss readers done
    *(int4*)(&Ks[srow * 72 + scg * 8]) = kv0;
    *(int4*)(&Ks[(srow + 32) * 72 + scg * 8]) = kv1;
    // issue ALL 16 E B-frag loads here (kv dead; latency overlaps the barrier
    // drain + ak ds_reads; consumed by the MFMA burst below) — R16: -4.3 µs
    int estart = (qt - kt) * 64 + 448;
    s16x8 ebf[16];
#pragma unroll
    for (int nf = 0; nf < 8; ++nf) {
      const s16x8* ep = (const s16x8*)(Eb + (size_t)(estart + nf * 16 + l15) * 64 + quad * 8);
      ebf[nf * 2] = ep[0];
      ebf[nf * 2 + 1] = ep[4];
    }
    __syncthreads();   // Ks visible
    s16x8 ak0 = *(const s16x8*)(&Ks[(wv * 16 + l15) * 72 + quad * 8]);
    s16x8 ak1 = *(const s16x8*)(&Ks[(wv * 16 + l15) * 72 + 32 + quad * 8]);
    // S1 = Q@E^T, S2 = K@E^T -> LDS col-major bf16 (dense MFMA burst)
#pragma unroll
    for (int nf = 0; nf < 8; ++nf) {
      f32x4 s1 = mfma16(aq1, ebf[nf * 2 + 1], mfma16(aq0, ebf[nf * 2], zero4()));
      s16x4 w1;
      w1.x = (short)f2b(s1[0]); w1.y = (short)f2b(s1[1]);
      w1.z = (short)f2b(s1[2]); w1.w = (short)f2b(s1[3]);
      *(s16x4*)(&Ss1[(nf * 16 + l15) * 68 + wv * 16 + quad * 4]) = w1;
      f32x4 s2 = mfma16(ak1, ebf[nf * 2 + 1], mfma16(ak0, ebf[nf * 2], zero4()));
      s16x4 w2;
      w2.x = (short)f2b(s2[0]); w2.y = (short)f2b(s2[1]);
      w2.z = (short)f2b(s2[2]); w2.w = (short)f2b(s2[3]);
      *(s16x4*)(&Ss2[(nf * 16 + l15) * 68 + wv * 16 + quad * 4]) = w2;
    }
    // QK^T stripe
    f32x4 s[4];
#pragma unroll
    for (int nf = 0; nf < 4; ++nf) {
      s16x8 b0 = *(const s16x8*)(&Ks[(nf * 16 + l15) * 72 + quad * 8]);
      s16x8 b1 = *(const s16x8*)(&Ks[(nf * 16 + l15) * 72 + 32 + quad * 8]);
      s[nf] = mfma16(aq1, b1, mfma16(aq0, b0, zero4()));
    }
    __syncthreads();   // Ss visible
#pragma unroll
    for (int nf = 0; nf < 4; ++nf) {
      int dr = nf * 16 + l15;
      float ex[4];
#pragma unroll
      for (int r = 0; r < 4; ++r) {
        int dl = wv * 16 + quad * 4 + r;
        int tt = dl - dr + 63;   // 0..126
        float p1 = b2f((unsigned short)Ss1[tt * 68 + dl]);
        float p2 = b2f((unsigned short)Ss2[tt * 68 + dr]);
        float x = (s[nf][r] + p1 + p2) * 0.125f + mkv[nf];
        ex[r] = __expf(x);
        lsum[r] += ex[r];
      }
      stash[kt * 8 + nf * 2 + 0] = packbf(ex[0], ex[1]);
      stash[kt * 8 + nf * 2 + 1] = packbf(ex[2], ex[3]);
    }
  }

  // cross-lane (l15 group) combine of row sums
#pragma unroll
  for (int r = 0; r < 4; ++r) {
    lsum[r] += __shfl_xor(lsum[r], 1);
    lsum[r] += __shfl_xor(lsum[r], 2);
    lsum[r] += __shfl_xor(lsum[r], 4);
    lsum[r] += __shfl_xor(lsum[r], 8);
  }
  float f1[4];
#pragma unroll
  for (int r = 0; r < 4; ++r) f1[r] = 1.0234375f / lsum[r];
  const float c0 = -0.0234375f;

  // ================= epilogue: p = clip(ex*f1 + c0) -> Ps -> P@V =================
  // Ps aliases Ks: Ks's last readers (kt=7 QK^T B-frags) are before the kt=7
  // "Ss visible" barrier, which every wave has passed. Ps is wave-local.
  short* Ps = Ks;

  f32x4 ctx[4];
#pragma unroll
  for (int nf = 0; nf < 4; ++nf) ctx[nf] = zero4();

#pragma unroll
  for (int kt = 0; kt < 8; ++kt) {
#pragma unroll
    for (int nf = 0; nf < 4; ++nf) {
      unsigned u0 = stash[kt * 8 + nf * 2 + 0];
      unsigned u1 = stash[kt * 8 + nf * 2 + 1];
      float e0 = b2f((unsigned short)(u0 & 0xffff));
      float e1 = b2f((unsigned short)(u0 >> 16));
      float e2 = b2f((unsigned short)(u1 & 0xffff));
      float e3 = b2f((unsigned short)(u1 >> 16));
      float p0 = fminf(fmaxf(e0 * f1[0] + c0, 0.0f), 1.0f);
      float p1 = fminf(fmaxf(e1 * f1[1] + c0, 0.0f), 1.0f);
      float p2 = fminf(fmaxf(e2 * f1[2] + c0, 0.0f), 1.0f);
      float p3 = fminf(fmaxf(e3 * f1[3] + c0, 0.0f), 1.0f);
      int rowb = wv * 16 + quad * 4;
      Ps[(rowb + 0) * 72 + nf * 16 + l15] = (short)f2b(p0);
      Ps[(rowb + 1) * 72 + nf * 16 + l15] = (short)f2b(p1);
      Ps[(rowb + 2) * 72 + nf * 16 + l15] = (short)f2b(p2);
      Ps[(rowb + 3) * 72 + nf * 16 + l15] = (short)f2b(p3);
    }
    // P@V for this tile (wave-local Ps; V B-frags direct from global)
    s16x8 ap0 = *(const s16x8*)(&Ps[(wv * 16 + l15) * 72 + quad * 8]);
    s16x8 ap1 = *(const s16x8*)(&Ps[(wv * 16 + l15) * 72 + 32 + quad * 8]);
#pragma unroll
    for (int nf = 0; nf < 4; ++nf) {
      const s16x8* vp = (const s16x8*)(Vt + ((size_t)bh * 64 + nf * 16 + l15) * 512 + kt * 64 + quad * 8);
      s16x8 vb0 = vp[0];
      s16x8 vb1 = vp[4];
      ctx[nf] = mfma16(ap1, vb1, mfma16(ap0, vb0, ctx[nf]));
    }
  }

  // ---- epilogue: * gate, write out [b][s][h*64+dh] fp32 ----
#pragma unroll
  for (int r = 0; r < 4; ++r) {
    int s = l0 + wv * 16 + quad * 4 + r;
    float g = gate[(size_t)bh * 512 + s];
#pragma unroll
    for (int nf = 0; nf < 4; ++nf)
      out[((size_t)(b * 512 + s)) * 1024 + hh * 64 + nf * 16 + l15] = ctx[nf][r] * g;
  }
}

// ---------- launch ----------
extern "C" void kernel_launch(void* const* d_in, const int* in_sizes, int n_in,
                              void* d_out, int out_size, void* d_ws, size_t ws_size,
                              hipStream_t stream) {
  const float* X = (const float*)d_in[0];
  const float* mask = (const float*)d_in[1];
  const float* Wq = (const float*)d_in[2];
  const float* bq = (const float*)d_in[3];
  const float* Wk = (const float*)d_in[4];
  const float* bk = (const float*)d_in[5];
  const float* Wv = (const float*)d_in[6];
  const float* bv = (const float*)d_in[7];
  const float* dist = (const float*)d_in[8];
  const float* gw = (const float*)d_in[9];
  const float* gb = (const float*)d_in[10];
  float* out = (float*)d_out;

  char* ws = (char*)d_ws;
  constexpr size_t OFF_XB = 0;                       // 8192*1024*2 = 16 MB
  constexpr size_t OFF_WT = 16777216;                // 3*1024*1024*2 = 6 MB
  constexpr size_t OFF_QB = OFF_WT + 6291456;        // 16 MB
  constexpr size_t OFF_KB = OFF_QB + 16777216;       // 16 MB
  constexpr size_t OFF_VT = OFF_KB + 16777216;       // 16 MB
  constexpr size_t OFF_EB = OFF_VT + 16777216;       // 1024*64*2
  constexpr size_t OFF_GA = OFF_EB + 131072;         // 256*512*4

  unsigned short* Xb = (unsigned short*)(ws + OFF_XB);
  unsigned short* Wt = (unsigned short*)(ws + OFF_WT);
  unsigned short* Qb = (unsigned short*)(ws + OFF_QB);
  unsigned short* Kb = (unsigned short*)(ws + OFF_KB);
  unsigned short* Vt = (unsigned short*)(ws + OFF_VT);
  unsigned short* Eb = (unsigned short*)(ws + OFF_EB);
  float* gate = (float*)(ws + OFF_GA);

  hipLaunchKernelGGL(k0_prep, dim3(9216), dim3(256), 0, stream,
                     X, gw, gb, Wq, Wk, Wv, dist, Xb, gate, Wt, Eb);
  hipLaunchKernelGGL(k1_qkv, dim3(64, 8, 3), dim3(256), 0, stream,
                     Xb, Wt, bq, bk, bv, Qb, Kb, Vt);
  hipLaunchKernelGGL(k2_attn, dim3(2048), dim3(256), 0, stream,
                     Qb, Kb, Vt, Eb, gate, mask, out);
}